// Round 1
// baseline (435.003 us; speedup 1.0000x reference)
//
#include <hip/hip_runtime.h>
#include <hip/hip_bf16.h>

typedef unsigned short u16;
typedef __attribute__((ext_vector_type(4))) float f32x4;
typedef __attribute__((ext_vector_type(8))) short bf16x8;
typedef __attribute__((ext_vector_type(8))) u16 u16x8;

#define GLDS16(g, l) __builtin_amdgcn_global_load_lds( \
    (const __attribute__((address_space(1))) void*)(g), \
    (__attribute__((address_space(3))) void*)(l), 16, 0, 0)

__device__ inline u16 f2bf(float f) {
  union { float f; unsigned u; } v; v.f = f;
  unsigned r = v.u + 0x7fffu + ((v.u >> 16) & 1u);
  return (u16)(r >> 16);
}

// ---------------------------------------------------------------------------
// Kernel 1: W[o][i] = (q[o][i]-8)*scale[o][i/32] + sum_r la[o][r]*lb[r][i]
// block = 16 rows x 512 cols, 256 threads; thread = 4 rows x 8 cols.
// lb strip staged in LDS (16x512 f32 = 32KB); la staged (256 f32).
// ---------------------------------------------------------------------------
__global__ __launch_bounds__(256) void k_dequant_lora(
    const int* __restrict__ qw, const float* __restrict__ sc,
    const float* __restrict__ la, const float* __restrict__ lb,
    u16* __restrict__ W)
{
  const int I = 4096, R = 16;
  __shared__ float lbs[16][512];
  __shared__ float las[256];
  const int c0 = blockIdx.x * 512;
  const int o0 = blockIdx.y * 16;
  const int tid = threadIdx.x;

  las[tid] = la[(size_t)(o0 + (tid >> 4)) * R + (tid & 15)];
  #pragma unroll
  for (int i = 0; i < 8; ++i) {
    int idx = tid + i * 256;        // 2048 float4 = 16 rows x 128
    int r = idx >> 7;
    int cc4 = (idx & 127) << 2;
    *(float4*)&lbs[r][cc4] = *(const float4*)&lb[(size_t)r * I + c0 + cc4];
  }
  __syncthreads();

  const int cc = (tid & 63) * 8;   // col within strip
  const int rg = tid >> 6;         // row group 0..3
  #pragma unroll
  for (int rr = 0; rr < 4; ++rr) {
    const int o = o0 + rg * 4 + rr;
    float acc[8] = {0.f,0.f,0.f,0.f,0.f,0.f,0.f,0.f};
    #pragma unroll
    for (int r = 0; r < 16; ++r) {
      float av = las[(rg * 4 + rr) * 16 + r];
      float4 b0 = *(const float4*)&lbs[r][cc];
      float4 b1 = *(const float4*)&lbs[r][cc + 4];
      acc[0] += av * b0.x; acc[1] += av * b0.y;
      acc[2] += av * b0.z; acc[3] += av * b0.w;
      acc[4] += av * b1.x; acc[5] += av * b1.y;
      acc[6] += av * b1.z; acc[7] += av * b1.w;
    }
    const int4* qp = (const int4*)&qw[(size_t)o * I + c0 + cc];
    int4 q0 = qp[0], q1 = qp[1];
    float s = sc[(size_t)o * (I / 32) + ((c0 + cc) >> 5)];
    u16x8 w;
    w[0] = f2bf(((float)q0.x - 8.0f) * s + acc[0]);
    w[1] = f2bf(((float)q0.y - 8.0f) * s + acc[1]);
    w[2] = f2bf(((float)q0.z - 8.0f) * s + acc[2]);
    w[3] = f2bf(((float)q0.w - 8.0f) * s + acc[3]);
    w[4] = f2bf(((float)q1.x - 8.0f) * s + acc[4]);
    w[5] = f2bf(((float)q1.y - 8.0f) * s + acc[5]);
    w[6] = f2bf(((float)q1.z - 8.0f) * s + acc[6]);
    w[7] = f2bf(((float)q1.w - 8.0f) * s + acc[7]);
    *(u16x8*)&W[(size_t)o * I + c0 + cc] = w;
  }
}

// ---------------------------------------------------------------------------
// Kernel 2: x (f32) -> bf16, vectorized 8/thread, grid-stride
// ---------------------------------------------------------------------------
__global__ __launch_bounds__(256) void k_cvt(const float* __restrict__ x,
                                             u16* __restrict__ xb)
{
  const size_t n = (size_t)8192 * 4096;
  const size_t stride = (size_t)gridDim.x * 256 * 8;
  for (size_t i = ((size_t)blockIdx.x * 256 + threadIdx.x) * 8; i < n; i += stride) {
    float4 a = *(const float4*)&x[i];
    float4 b = *(const float4*)&x[i + 4];
    u16x8 o;
    o[0] = f2bf(a.x); o[1] = f2bf(a.y); o[2] = f2bf(a.z); o[3] = f2bf(a.w);
    o[4] = f2bf(b.x); o[5] = f2bf(b.y); o[6] = f2bf(b.z); o[7] = f2bf(b.w);
    *(u16x8*)&xb[i] = o;
  }
}

// ---------------------------------------------------------------------------
// Kernel 3: C[M,N] = A[M,K] @ B[N,K]^T + bias   (m97 structure)
// 128x128 tile, BK=32, 4 waves (2x2), each wave 64x64 via 4x4 of 16x16x32 MFMA
// global_load_lds width-16 staging, 2-barrier K-loop, XCD swizzle.
// ---------------------------------------------------------------------------
__global__ __launch_bounds__(256) void k_gemm(
    const u16* __restrict__ A, const u16* __restrict__ B,
    const float* __restrict__ bias, float* __restrict__ C)
{
  const int M = 8192, N = 4096, K = 4096;
  (void)M;
  __shared__ u16 As[128 * 32];
  __shared__ u16 Bs[128 * 32];

  // XCD-aware swizzle (gridDim.x = 2048, divisible by 8 -> bijective)
  const int nwg = gridDim.x;
  const int cpx = nwg >> 3;
  const int bid = blockIdx.x;
  const int swz = (bid & 7) * cpx + (bid >> 3);
  const int ntn = N / 128;
  const int m0 = (swz / ntn) * 128;
  const int n0 = (swz % ntn) * 128;

  const int tid = threadIdx.x;
  const int wave = tid >> 6, lane = tid & 63;
  const int wm = (wave >> 1) * 64, wn = (wave & 1) * 64;
  const int fr = lane & 15;          // M/N index within 16x16 fragment
  const int fk = (lane >> 4) * 8;    // K offset within fragment

  // staging: tile is 128 rows x 32 cols bf16 = 8KB = 8 chunks of 1024B.
  // chunk c = r*4 + wave (r=0,1); lane l covers row c*16 + l/4, cols (l&3)*8..+7
  const int srow0 = wave * 16 + (lane >> 2);
  const int scol = (lane & 3) * 8;
  const u16* Ag0 = A + (size_t)(m0 + srow0) * K + scol;
  const u16* Ag1 = Ag0 + (size_t)64 * K;
  const u16* Bg0 = B + (size_t)(n0 + srow0) * K + scol;
  const u16* Bg1 = Bg0 + (size_t)64 * K;
  u16* Asd0 = &As[(size_t)wave * 512];
  u16* Asd1 = &As[(size_t)(4 + wave) * 512];
  u16* Bsd0 = &Bs[(size_t)wave * 512];
  u16* Bsd1 = &Bs[(size_t)(4 + wave) * 512];

  f32x4 acc[4][4] = {};

  for (int k0 = 0; k0 < K; k0 += 32) {
    __syncthreads();                 // previous tile's reads done
    GLDS16(Ag0 + k0, Asd0);
    GLDS16(Ag1 + k0, Asd1);
    GLDS16(Bg0 + k0, Bsd0);
    GLDS16(Bg1 + k0, Bsd1);
    __syncthreads();                 // staging visible (vmcnt(0) before barrier)

    bf16x8 a[4], b[4];
    #pragma unroll
    for (int m = 0; m < 4; ++m)
      a[m] = *(const bf16x8*)&As[(wm + m * 16 + fr) * 32 + fk];
    #pragma unroll
    for (int n = 0; n < 4; ++n)
      b[n] = *(const bf16x8*)&Bs[(wn + n * 16 + fr) * 32 + fk];
    #pragma unroll
    for (int m = 0; m < 4; ++m)
      #pragma unroll
      for (int n = 0; n < 4; ++n)
        acc[m][n] = __builtin_amdgcn_mfma_f32_16x16x32_bf16(a[m], b[n], acc[m][n], 0, 0, 0);
  }

  // C/D layout (m89-verified): col = lane&15, row = (lane>>4)*4 + reg
  const int crow = m0 + wm + (lane >> 4) * 4;
  const int ccol = n0 + wn + fr;
  #pragma unroll
  for (int n = 0; n < 4; ++n) {
    float bv = bias[ccol + n * 16];
    #pragma unroll
    for (int m = 0; m < 4; ++m) {
      #pragma unroll
      for (int j = 0; j < 4; ++j) {
        C[(size_t)(crow + m * 16 + j) * N + ccol + n * 16] = acc[m][n][j] + bv;
      }
    }
  }
}

// ---------------------------------------------------------------------------
extern "C" void kernel_launch(void* const* d_in, const int* in_sizes, int n_in,
                              void* d_out, int out_size, void* d_ws, size_t ws_size,
                              hipStream_t stream) {
  const float* x    = (const float*)d_in[0];   // [8192, 4096] f32
  const int*   qw   = (const int*)d_in[1];     // [4096, 4096] i32
  const float* sc   = (const float*)d_in[2];   // [4096, 128]  f32
  const float* la   = (const float*)d_in[3];   // [4096, 16]   f32
  const float* lb   = (const float*)d_in[4];   // [16, 4096]   f32
  const float* bias = (const float*)d_in[5];   // [4096]       f32
  float* y = (float*)d_out;                    // [8192, 4096] f32

  u16* W  = (u16*)d_ws;                                        // 32 MiB
  u16* Xb = (u16*)((char*)d_ws + (size_t)32 * 1024 * 1024);    // 64 MiB

  dim3 gridD(4096 / 512, 4096 / 16);
  k_dequant_lora<<<gridD, 256, 0, stream>>>(qw, sc, la, lb, W);
  k_cvt<<<2048, 256, 0, stream>>>(x, Xb);
  const int ngemm = (8192 / 128) * (4096 / 128);   // 2048
  k_gemm<<<ngemm, 256, 0, stream>>>(Xb, W, bias, y);
}

// Round 2
// 372.003 us; speedup vs baseline: 1.1694x; 1.1694x over previous
//
#include <hip/hip_runtime.h>
#include <hip/hip_bf16.h>

typedef unsigned short u16;
typedef __attribute__((ext_vector_type(4))) float f32x4;
typedef __attribute__((ext_vector_type(8))) short bf16x8;
typedef __attribute__((ext_vector_type(8))) u16 u16x8;

#define GLDS16(g, l) __builtin_amdgcn_global_load_lds( \
    (const __attribute__((address_space(1))) void*)(g), \
    (__attribute__((address_space(3))) void*)(l), 16, 0, 0)

__device__ inline u16 f2bf(float f) {
  union { float f; unsigned u; } v; v.f = f;
  unsigned r = v.u + 0x7fffu + ((v.u >> 16) & 1u);
  return (u16)(r >> 16);
}

// ---------------------------------------------------------------------------
// Kernel 1: W[o][i] = (q[o][i]-8)*scale[o][i/32] + sum_r la[o][r]*lb[r][i]
// ---------------------------------------------------------------------------
__global__ __launch_bounds__(256) void k_dequant_lora(
    const int* __restrict__ qw, const float* __restrict__ sc,
    const float* __restrict__ la, const float* __restrict__ lb,
    u16* __restrict__ W)
{
  const int I = 4096, R = 16;
  __shared__ float lbs[16][512];
  __shared__ float las[256];
  const int c0 = blockIdx.x * 512;
  const int o0 = blockIdx.y * 16;
  const int tid = threadIdx.x;

  las[tid] = la[(size_t)(o0 + (tid >> 4)) * R + (tid & 15)];
  #pragma unroll
  for (int i = 0; i < 8; ++i) {
    int idx = tid + i * 256;
    int r = idx >> 7;
    int cc4 = (idx & 127) << 2;
    *(float4*)&lbs[r][cc4] = *(const float4*)&lb[(size_t)r * I + c0 + cc4];
  }
  __syncthreads();

  const int cc = (tid & 63) * 8;
  const int rg = tid >> 6;
  #pragma unroll
  for (int rr = 0; rr < 4; ++rr) {
    const int o = o0 + rg * 4 + rr;
    float acc[8] = {0.f,0.f,0.f,0.f,0.f,0.f,0.f,0.f};
    #pragma unroll
    for (int r = 0; r < 16; ++r) {
      float av = las[(rg * 4 + rr) * 16 + r];
      float4 b0 = *(const float4*)&lbs[r][cc];
      float4 b1 = *(const float4*)&lbs[r][cc + 4];
      acc[0] += av * b0.x; acc[1] += av * b0.y;
      acc[2] += av * b0.z; acc[3] += av * b0.w;
      acc[4] += av * b1.x; acc[5] += av * b1.y;
      acc[6] += av * b1.z; acc[7] += av * b1.w;
    }
    const int4* qp = (const int4*)&qw[(size_t)o * I + c0 + cc];
    int4 q0 = qp[0], q1 = qp[1];
    float s = sc[(size_t)o * (I / 32) + ((c0 + cc) >> 5)];
    u16x8 w;
    w[0] = f2bf(((float)q0.x - 8.0f) * s + acc[0]);
    w[1] = f2bf(((float)q0.y - 8.0f) * s + acc[1]);
    w[2] = f2bf(((float)q0.z - 8.0f) * s + acc[2]);
    w[3] = f2bf(((float)q0.w - 8.0f) * s + acc[3]);
    w[4] = f2bf(((float)q1.x - 8.0f) * s + acc[4]);
    w[5] = f2bf(((float)q1.y - 8.0f) * s + acc[5]);
    w[6] = f2bf(((float)q1.z - 8.0f) * s + acc[6]);
    w[7] = f2bf(((float)q1.w - 8.0f) * s + acc[7]);
    *(u16x8*)&W[(size_t)o * I + c0 + cc] = w;
  }
}

// ---------------------------------------------------------------------------
// Kernel 2: x (f32) -> bf16
// ---------------------------------------------------------------------------
__global__ __launch_bounds__(256) void k_cvt(const float* __restrict__ x,
                                             u16* __restrict__ xb)
{
  const size_t n = (size_t)8192 * 4096;
  const size_t stride = (size_t)gridDim.x * 256 * 8;
  for (size_t i = ((size_t)blockIdx.x * 256 + threadIdx.x) * 8; i < n; i += stride) {
    float4 a = *(const float4*)&x[i];
    float4 b = *(const float4*)&x[i + 4];
    u16x8 o;
    o[0] = f2bf(a.x); o[1] = f2bf(a.y); o[2] = f2bf(a.z); o[3] = f2bf(a.w);
    o[4] = f2bf(b.x); o[5] = f2bf(b.y); o[6] = f2bf(b.z); o[7] = f2bf(b.w);
    *(u16x8*)&xb[i] = o;
  }
}

// ---------------------------------------------------------------------------
// Kernel 3: C[M,N] = A[M,K] @ B[N,K]^T + bias
// 256x256 tile, BK=32, 4-deep LDS ring, 8 waves (2Mx4N), 512 threads.
// Deep pipeline: compute tile t while staging tile t+2 (buffer free since
// group t-2 -> WAR race-free). Counted vmcnt(4) gate once per K-tile.
// st_16x32 XOR swizzle: linear global_load_lds dest + inverse-swizzled
// per-lane global source + swizzled ds_read -> 4-way residual conflict.
// ---------------------------------------------------------------------------
__global__ __launch_bounds__(512, 2) void k_gemm(
    const u16* __restrict__ A, const u16* __restrict__ B,
    const float* __restrict__ bias, float* __restrict__ C)
{
  const int N = 4096, K = 4096;
  const int NTK = 128;                 // K / 32
  __shared__ u16 As[4 * 8192];         // 4 ring buffers x [256 rows][32 k]
  __shared__ u16 Bs[4 * 8192];

  // XCD swizzle: 512 blocks = 8 XCDs x 64
  const int bid = blockIdx.x;
  const int swz = (bid & 7) * 64 + (bid >> 3);
  const int m0 = (swz >> 4) * 256;     // 32 M-tiles
  const int n0 = (swz & 15) * 256;     // 16 N-tiles

  const int tid = threadIdx.x;
  const int wid = tid >> 6, lane = tid & 63;
  const int wid_m = wid >> 2, wid_n = wid & 3;

  // ---- staging geometry: one gload_lds issue fills one 1024B subtile ----
  // subtile st covers tile rows [st*16, st*16+16) x k [0,32)
  // lane l -> subtile row r=l>>2, chunk (l&3); global chunk = (l&3)^((r&8)?2:0)
  const int st0 = wid;                 // issue 0 subtile
  const int st1 = 8 + wid;             // issue 1 subtile
  const int srow = lane >> 2;
  const int schunk = (((lane & 3) ^ (((lane >> 5) & 1) << 1))) * 8;
  const u16* Asrc0 = A + (size_t)(m0 + st0 * 16 + srow) * K + schunk;
  const u16* Asrc1 = A + (size_t)(m0 + st1 * 16 + srow) * K + schunk;
  const u16* Bsrc0 = B + (size_t)(n0 + st0 * 16 + srow) * K + schunk;
  const u16* Bsrc1 = B + (size_t)(n0 + st1 * 16 + srow) * K + schunk;

  #define STAGE_A(buf, t) do { \
    GLDS16(Asrc0 + (size_t)(t) * 32, &As[(buf) * 8192 + st0 * 512]); \
    GLDS16(Asrc1 + (size_t)(t) * 32, &As[(buf) * 8192 + st1 * 512]); } while (0)
  #define STAGE_B(buf, t) do { \
    GLDS16(Bsrc0 + (size_t)(t) * 32, &Bs[(buf) * 8192 + st0 * 512]); \
    GLDS16(Bsrc1 + (size_t)(t) * 32, &Bs[(buf) * 8192 + st1 * 512]); } while (0)

  // ---- fragment read offsets (swizzled) ----
  // row = frag_base*16 + (lane&15), k = (lane>>4)*8; elem =
  // (row>>4)*512 + (row&15)*32 + (k ^ ((row&8)?16:0))
  const int LA = (lane & 15) * 32 + (((lane >> 4) * 8) ^ ((lane & 8) ? 16 : 0));
  const int wmb = wid_m * 8;           // A subtile base (8 m-frags)
  const int wnb = wid_n * 4;           // B subtile base (4 n-frags)

  f32x4 acc[8][4] = {};

  // ---- prologue: stage tiles 0 and 1 ----
  STAGE_A(0, 0); STAGE_B(0, 0);
  STAGE_A(1, 1); STAGE_B(1, 1);
  asm volatile("s_waitcnt vmcnt(4)" ::: "memory");   // tile 0 landed
  __builtin_amdgcn_s_barrier();

  for (int t = 0; t < NTK; ++t) {
    const int b = t & 3;
    const u16* Ab = &As[b * 8192];
    const u16* Bb = &Bs[b * 8192];

    // ======== phase 0: m-frags 0..3, all B-frags ========
    bf16x8 af[4], bfr[4];
    #pragma unroll
    for (int m = 0; m < 4; ++m)
      af[m] = *(const bf16x8*)&Ab[(wmb + m) * 512 + LA];
    #pragma unroll
    for (int n = 0; n < 4; ++n)
      bfr[n] = *(const bf16x8*)&Bb[(wnb + n) * 512 + LA];
    if (t + 2 < NTK) STAGE_A((t + 2) & 3, t + 2);
    __builtin_amdgcn_s_barrier();
    asm volatile("s_waitcnt lgkmcnt(0)" ::: "memory");
    __builtin_amdgcn_s_setprio(1);
    #pragma unroll
    for (int m = 0; m < 4; ++m)
      #pragma unroll
      for (int n = 0; n < 4; ++n)
        acc[m][n] = __builtin_amdgcn_mfma_f32_16x16x32_bf16(af[m], bfr[n], acc[m][n], 0, 0, 0);
    __builtin_amdgcn_s_setprio(0);
    __builtin_amdgcn_s_barrier();

    // ======== phase 1: m-frags 4..7 (B reused in regs) ========
    bf16x8 af2[4];
    #pragma unroll
    for (int m = 0; m < 4; ++m)
      af2[m] = *(const bf16x8*)&Ab[(wmb + 4 + m) * 512 + LA];
    if (t + 2 < NTK) {
      STAGE_B((t + 2) & 3, t + 2);
      // gate tile t+1 (staged last group): allow only tile t+2's 4 loads
      asm volatile("s_waitcnt vmcnt(4)" ::: "memory");
    } else {
      asm volatile("s_waitcnt vmcnt(0)" ::: "memory");
    }
    __builtin_amdgcn_s_barrier();
    asm volatile("s_waitcnt lgkmcnt(0)" ::: "memory");
    __builtin_amdgcn_s_setprio(1);
    #pragma unroll
    for (int m = 0; m < 4; ++m)
      #pragma unroll
      for (int n = 0; n < 4; ++n)
        acc[4 + m][n] = __builtin_amdgcn_mfma_f32_16x16x32_bf16(af2[m], bfr[n], acc[4 + m][n], 0, 0, 0);
    __builtin_amdgcn_s_setprio(0);
    __builtin_amdgcn_s_barrier();
  }
  #undef STAGE_A
  #undef STAGE_B

  // ---- epilogue: C/D layout col=lane&15, row=(lane>>4)*4+j ----
  const int crow = m0 + wid_m * 128 + ((lane >> 4) << 2);
  const int ccol = n0 + wid_n * 64 + (lane & 15);
  #pragma unroll
  for (int n = 0; n < 4; ++n) {
    float bv = bias[ccol + n * 16];
    #pragma unroll
    for (int m = 0; m < 8; ++m) {
      #pragma unroll
      for (int j = 0; j < 4; ++j) {
        C[(size_t)(crow + m * 16 + j) * N + ccol + n * 16] = acc[m][n][j] + bv;
      }
    }
  }
}

// ---------------------------------------------------------------------------
extern "C" void kernel_launch(void* const* d_in, const int* in_sizes, int n_in,
                              void* d_out, int out_size, void* d_ws, size_t ws_size,
                              hipStream_t stream) {
  const float* x    = (const float*)d_in[0];   // [8192, 4096] f32
  const int*   qw   = (const int*)d_in[1];     // [4096, 4096] i32
  const float* sc   = (const float*)d_in[2];   // [4096, 128]  f32
  const float* la   = (const float*)d_in[3];   // [4096, 16]   f32
  const float* lb   = (const float*)d_in[4];   // [16, 4096]   f32
  const float* bias = (const float*)d_in[5];   // [4096]       f32
  float* y = (float*)d_out;                    // [8192, 4096] f32

  u16* W  = (u16*)d_ws;                                        // 32 MiB
  u16* Xb = (u16*)((char*)d_ws + (size_t)32 * 1024 * 1024);    // 64 MiB

  dim3 gridD(4096 / 512, 4096 / 16);
  k_dequant_lora<<<gridD, 256, 0, stream>>>(qw, sc, la, lb, W);
  k_cvt<<<2048, 256, 0, stream>>>(x, Xb);
  const int ngemm = (8192 / 256) * (4096 / 256);   // 512
  k_gemm<<<ngemm, 512, 0, stream>>>(Xb, W, bias, y);
}

// Round 3
// 357.356 us; speedup vs baseline: 1.2173x; 1.0410x over previous
//
#include <hip/hip_runtime.h>
#include <hip/hip_bf16.h>

typedef unsigned short u16;
typedef __attribute__((ext_vector_type(4))) float f32x4;
typedef __attribute__((ext_vector_type(8))) short bf16x8;
typedef __attribute__((ext_vector_type(8))) u16 u16x8;

#define GLDS16(g, l) __builtin_amdgcn_global_load_lds( \
    (const __attribute__((address_space(1))) void*)(g), \
    (__attribute__((address_space(3))) void*)(l), 16, 0, 0)

__device__ inline u16 f2bf(float f) {
  union { float f; unsigned u; } v; v.f = f;
  unsigned r = v.u + 0x7fffu + ((v.u >> 16) & 1u);
  return (u16)(r >> 16);
}

// ---------------------------------------------------------------------------
// Kernel 1: W[o][i] = (q[o][i]-8)*scale[o][i/32] + sum_r la[o][r]*lb[r][i]
// ---------------------------------------------------------------------------
__global__ __launch_bounds__(256) void k_dequant_lora(
    const int* __restrict__ qw, const float* __restrict__ sc,
    const float* __restrict__ la, const float* __restrict__ lb,
    u16* __restrict__ W)
{
  const int I = 4096, R = 16;
  __shared__ float lbs[16][512];
  __shared__ float las[256];
  const int c0 = blockIdx.x * 512;
  const int o0 = blockIdx.y * 16;
  const int tid = threadIdx.x;

  las[tid] = la[(size_t)(o0 + (tid >> 4)) * R + (tid & 15)];
  #pragma unroll
  for (int i = 0; i < 8; ++i) {
    int idx = tid + i * 256;
    int r = idx >> 7;
    int cc4 = (idx & 127) << 2;
    *(float4*)&lbs[r][cc4] = *(const float4*)&lb[(size_t)r * I + c0 + cc4];
  }
  __syncthreads();

  const int cc = (tid & 63) * 8;
  const int rg = tid >> 6;
  #pragma unroll
  for (int rr = 0; rr < 4; ++rr) {
    const int o = o0 + rg * 4 + rr;
    float acc[8] = {0.f,0.f,0.f,0.f,0.f,0.f,0.f,0.f};
    #pragma unroll
    for (int r = 0; r < 16; ++r) {
      float av = las[(rg * 4 + rr) * 16 + r];
      float4 b0 = *(const float4*)&lbs[r][cc];
      float4 b1 = *(const float4*)&lbs[r][cc + 4];
      acc[0] += av * b0.x; acc[1] += av * b0.y;
      acc[2] += av * b0.z; acc[3] += av * b0.w;
      acc[4] += av * b1.x; acc[5] += av * b1.y;
      acc[6] += av * b1.z; acc[7] += av * b1.w;
    }
    const int4* qp = (const int4*)&qw[(size_t)o * I + c0 + cc];
    int4 q0 = qp[0], q1 = qp[1];
    float s = sc[(size_t)o * (I / 32) + ((c0 + cc) >> 5)];
    u16x8 w;
    w[0] = f2bf(((float)q0.x - 8.0f) * s + acc[0]);
    w[1] = f2bf(((float)q0.y - 8.0f) * s + acc[1]);
    w[2] = f2bf(((float)q0.z - 8.0f) * s + acc[2]);
    w[3] = f2bf(((float)q0.w - 8.0f) * s + acc[3]);
    w[4] = f2bf(((float)q1.x - 8.0f) * s + acc[4]);
    w[5] = f2bf(((float)q1.y - 8.0f) * s + acc[5]);
    w[6] = f2bf(((float)q1.z - 8.0f) * s + acc[6]);
    w[7] = f2bf(((float)q1.w - 8.0f) * s + acc[7]);
    *(u16x8*)&W[(size_t)o * I + c0 + cc] = w;
  }
}

// ---------------------------------------------------------------------------
// Kernel 2: x (f32) -> bf16
// ---------------------------------------------------------------------------
__global__ __launch_bounds__(256) void k_cvt(const float* __restrict__ x,
                                             u16* __restrict__ xb)
{
  const size_t n = (size_t)8192 * 4096;
  const size_t stride = (size_t)gridDim.x * 256 * 8;
  for (size_t i = ((size_t)blockIdx.x * 256 + threadIdx.x) * 8; i < n; i += stride) {
    float4 a = *(const float4*)&x[i];
    float4 b = *(const float4*)&x[i + 4];
    u16x8 o;
    o[0] = f2bf(a.x); o[1] = f2bf(a.y); o[2] = f2bf(a.z); o[3] = f2bf(a.w);
    o[4] = f2bf(b.x); o[5] = f2bf(b.y); o[6] = f2bf(b.z); o[7] = f2bf(b.w);
    *(u16x8*)&xb[i] = o;
  }
}

// ---------------------------------------------------------------------------
// Kernel 3: C[M,N] = A[M,K] @ B[N,K]^T + bias
// 256x256 tile, BK=32, 4-deep LDS ring, 8 waves (2Mx4N), 512 threads.
// Round-3 change: cross-phase SOFTWARE PIPELINE of fragment ds_reads.
// Each phase's ds_read_b128s are issued during the PREVIOUS phase's MFMA
// (register double-buffer aC/aN, bA/bB), so LDS pipe overlaps matrix pipe.
// One s_barrier per K-tile (WAR protected by 2-barrier aging on the 4-ring;
// RAW by counted vmcnt(4) before the barrier). Compiler emits counted
// lgkmcnt from SSA deps; sched_barrier(0) pins region order.
// ---------------------------------------------------------------------------
__global__ __launch_bounds__(512, 2) void k_gemm(
    const u16* __restrict__ A, const u16* __restrict__ B,
    const float* __restrict__ bias, float* __restrict__ C)
{
  const int N = 4096, K = 4096;
  const int NTK = 128;                 // K / 32
  __shared__ u16 As[4 * 8192];         // 4 ring buffers x [256 rows][32 k]
  __shared__ u16 Bs[4 * 8192];

  // XCD swizzle: 512 blocks = 8 XCDs x 64
  const int bid = blockIdx.x;
  const int swz = (bid & 7) * 64 + (bid >> 3);
  const int m0 = (swz >> 4) * 256;     // 32 M-tiles
  const int n0 = (swz & 15) * 256;     // 16 N-tiles

  const int tid = threadIdx.x;
  const int wid = tid >> 6, lane = tid & 63;
  const int wid_m = wid >> 2, wid_n = wid & 3;

  // staging geometry (unchanged from round 2, refcheck-passed)
  const int st0 = wid;
  const int st1 = 8 + wid;
  const int srow = lane >> 2;
  const int schunk = (((lane & 3) ^ (((lane >> 5) & 1) << 1))) * 8;
  const u16* Asrc0 = A + (size_t)(m0 + st0 * 16 + srow) * K + schunk;
  const u16* Asrc1 = A + (size_t)(m0 + st1 * 16 + srow) * K + schunk;
  const u16* Bsrc0 = B + (size_t)(n0 + st0 * 16 + srow) * K + schunk;
  const u16* Bsrc1 = B + (size_t)(n0 + st1 * 16 + srow) * K + schunk;

#define STAGE_A(buf, t) do { \
    GLDS16(Asrc0 + (size_t)(t) * 32, &As[(buf) * 8192 + st0 * 512]); \
    GLDS16(Asrc1 + (size_t)(t) * 32, &As[(buf) * 8192 + st1 * 512]); } while (0)
#define STAGE_B(buf, t) do { \
    GLDS16(Bsrc0 + (size_t)(t) * 32, &Bs[(buf) * 8192 + st0 * 512]); \
    GLDS16(Bsrc1 + (size_t)(t) * 32, &Bs[(buf) * 8192 + st1 * 512]); } while (0)

  // swizzled fragment read offset (unchanged, 0 bank conflicts measured)
  const int LA = (lane & 15) * 32 + (((lane >> 4) * 8) ^ ((lane & 8) ? 16 : 0));
  const int wmb = wid_m * 8;           // A frag base (8 m-frags per wave)
  const int wnb = wid_n * 4;           // B frag base (4 n-frags per wave)

  f32x4 acc[8][4] = {};
  bf16x8 aC[4], aN[4], bA[4], bB[4];   // register double-buffers

  // ---- prologue: stage tiles 0,1; wait tile 0; issue tile-0 frag reads ----
  STAGE_A(0, 0); STAGE_B(0, 0);
  STAGE_A(1, 1); STAGE_B(1, 1);
  asm volatile("s_waitcnt vmcnt(4)" ::: "memory");   // tile 0 landed
  __builtin_amdgcn_s_barrier();
  __builtin_amdgcn_sched_barrier(0);
  #pragma unroll
  for (int m = 0; m < 4; ++m)
    aC[m] = *(const bf16x8*)&As[(wmb + m) * 512 + LA];
  #pragma unroll
  for (int n = 0; n < 4; ++n)
    bA[n] = *(const bf16x8*)&Bs[(wnb + n) * 512 + LA];

  // Per tile T (2 phases, ONE barrier):
  //  P0: issue aN<-A4-7(T); STAGE_A(T+2); MFMA m0-3 (aC,BCUR)
  //  P1: STAGE_B(T+2); vmcnt(4); barrier; issue aC<-A0-3(T+1), BNXT<-B(T+1);
  //      MFMA m4-7 (aN,BCUR)
#define TILE(T, BCUR, BNXT) do { \
    const int b_ = (T) & 3; \
    const int bn_ = ((T) + 1) & 3; \
    _Pragma("unroll") \
    for (int m = 0; m < 4; ++m) \
      aN[m] = *(const bf16x8*)&As[b_ * 8192 + (wmb + 4 + m) * 512 + LA]; \
    if ((T) + 2 < NTK) STAGE_A(((T) + 2) & 3, (T) + 2); \
    __builtin_amdgcn_sched_barrier(0); \
    __builtin_amdgcn_s_setprio(1); \
    _Pragma("unroll") \
    for (int m = 0; m < 4; ++m) { \
      _Pragma("unroll") \
      for (int n = 0; n < 4; ++n) \
        acc[m][n] = __builtin_amdgcn_mfma_f32_16x16x32_bf16(aC[m], BCUR[n], acc[m][n], 0, 0, 0); \
    } \
    __builtin_amdgcn_s_setprio(0); \
    __builtin_amdgcn_sched_barrier(0); \
    if ((T) + 2 < NTK) { \
      STAGE_B(((T) + 2) & 3, (T) + 2); \
      asm volatile("s_waitcnt vmcnt(4)" ::: "memory"); \
    } else { \
      asm volatile("s_waitcnt vmcnt(0)" ::: "memory"); \
    } \
    __builtin_amdgcn_s_barrier(); \
    __builtin_amdgcn_sched_barrier(0); \
    if ((T) + 1 < NTK) { \
      _Pragma("unroll") \
      for (int m = 0; m < 4; ++m) \
        aC[m] = *(const bf16x8*)&As[bn_ * 8192 + (wmb + m) * 512 + LA]; \
      _Pragma("unroll") \
      for (int n = 0; n < 4; ++n) \
        BNXT[n] = *(const bf16x8*)&Bs[bn_ * 8192 + (wnb + n) * 512 + LA]; \
    } \
    __builtin_amdgcn_sched_barrier(0); \
    __builtin_amdgcn_s_setprio(1); \
    _Pragma("unroll") \
    for (int m = 0; m < 4; ++m) { \
      _Pragma("unroll") \
      for (int n = 0; n < 4; ++n) \
        acc[4 + m][n] = __builtin_amdgcn_mfma_f32_16x16x32_bf16(aN[m], BCUR[n], acc[4 + m][n], 0, 0, 0); \
    } \
    __builtin_amdgcn_s_setprio(0); \
    __builtin_amdgcn_sched_barrier(0); \
  } while (0)

  for (int t = 0; t < NTK; t += 2) {
    TILE(t, bA, bB);
    TILE(t + 1, bB, bA);
  }
#undef TILE
#undef STAGE_A
#undef STAGE_B

  // ---- epilogue: C/D layout col=lane&15, row=(lane>>4)*4+j ----
  const int crow = m0 + wid_m * 128 + ((lane >> 4) << 2);
  const int ccol = n0 + wid_n * 64 + (lane & 15);
  #pragma unroll
  for (int n = 0; n < 4; ++n) {
    float bv = bias[ccol + n * 16];
    #pragma unroll
    for (int m = 0; m < 8; ++m) {
      #pragma unroll
      for (int j = 0; j < 4; ++j) {
        C[(size_t)(crow + m * 16 + j) * N + ccol + n * 16] = acc[m][n][j] + bv;
      }
    }
  }
}

// ---------------------------------------------------------------------------
extern "C" void kernel_launch(void* const* d_in, const int* in_sizes, int n_in,
                              void* d_out, int out_size, void* d_ws, size_t ws_size,
                              hipStream_t stream) {
  const float* x    = (const float*)d_in[0];   // [8192, 4096] f32
  const int*   qw   = (const int*)d_in[1];     // [4096, 4096] i32
  const float* sc   = (const float*)d_in[2];   // [4096, 128]  f32
  const float* la   = (const float*)d_in[3];   // [4096, 16]   f32
  const float* lb   = (const float*)d_in[4];   // [16, 4096]   f32
  const float* bias = (const float*)d_in[5];   // [4096]       f32
  float* y = (float*)d_out;                    // [8192, 4096] f32

  u16* W  = (u16*)d_ws;                                        // 32 MiB
  u16* Xb = (u16*)((char*)d_ws + (size_t)32 * 1024 * 1024);    // 64 MiB

  dim3 gridD(4096 / 512, 4096 / 16);
  k_dequant_lora<<<gridD, 256, 0, stream>>>(qw, sc, la, lb, W);
  k_cvt<<<2048, 256, 0, stream>>>(x, Xb);
  const int ngemm = (8192 / 256) * (4096 / 256);   // 512
  k_gemm<<<ngemm, 512, 0, stream>>>(Xb, W, bias, y);
}